// Round 1
// baseline (377.133 us; speedup 1.0000x reference)
//
#include <hip/hip_runtime.h>
#include <stdint.h>

#define DEV __device__ __forceinline__

typedef __bf16 bf16;
typedef __bf16 bf16x8 __attribute__((ext_vector_type(8)));
typedef float f32x4 __attribute__((ext_vector_type(4)));

static constexpr int S = 2048, D = 1024, NH = 16, DK = 64;
// fold 1/sqrt(DK) * log2(e) into Q so softmax runs in exp2 domain
static constexpr float QSCALE = 0.125f * 1.44269504088896340736f;

// ---------------- f32 -> bf16 convert, 8 elems/thread ----------------
__global__ __launch_bounds__(256) void cvt_kernel(const float* __restrict__ in,
                                                  bf16* __restrict__ out, int n8) {
  int i = blockIdx.x * 256 + threadIdx.x;
  if (i >= n8) return;
  const float4* p = (const float4*)in + (size_t)i * 2;
  float4 a = p[0], b = p[1];
  bf16x8 o;
  o[0] = (bf16)a.x; o[1] = (bf16)a.y; o[2] = (bf16)a.z; o[3] = (bf16)a.w;
  o[4] = (bf16)b.x; o[5] = (bf16)b.y; o[6] = (bf16)b.z; o[7] = (bf16)b.w;
  ((bf16x8*)out)[i] = o;
}

// ---------------- async global->LDS 16B ----------------
DEV void async_copy16(bf16* lds_dst, const bf16* g_src) {
  __builtin_amdgcn_global_load_lds(
      (const __attribute__((address_space(1))) void*)(g_src),
      (__attribute__((address_space(3))) void*)(lds_dst),
      16, 0, 0);
}

// ---------------- C = A * Bt^T + bias,  A[M,K], Bt[N,K] ----------------
// m97-structure: 128x128 tile, BK=32, 4 waves each 64x64, 16x16x32 bf16 MFMA.
template <bool OUT_F32>
__global__ __launch_bounds__(256, 2)
void gemm_bt(const bf16* __restrict__ A, const bf16* __restrict__ Bt,
             const float* __restrict__ bias,
             bf16* __restrict__ Cb, float* __restrict__ Cf,
             int M, int N, int K, float scale) {
  __shared__ bf16 As[128 * 32];
  __shared__ bf16 Bs[128 * 32];
  const int t = threadIdx.x;
  const int w = t >> 6, l = t & 63;
  const int wr = w >> 1, wc = w & 1;
  const int lr = l & 15, lg = l >> 4;
  const int m0 = blockIdx.y * 128, n0 = blockIdx.x * 128;

  f32x4 acc[4][4] = {};

  const int srow = t >> 2, scol = (t & 3) * 8;
  const bf16* Aptr = A + (size_t)(m0 + srow) * K + scol;
  const bf16* Bptr = Bt + (size_t)(n0 + srow) * K + scol;
  bf16* AsDst = &As[w * 512];  // wave-uniform base; HW adds lane*16B
  bf16* BsDst = &Bs[w * 512];

  for (int k0 = 0; k0 < K; k0 += 32) {
    async_copy16(AsDst,        Aptr + k0);
    async_copy16(AsDst + 2048, Aptr + (size_t)64 * K + k0);
    async_copy16(BsDst,        Bptr + k0);
    async_copy16(BsDst + 2048, Bptr + (size_t)64 * K + k0);
    __syncthreads();  // drains vmcnt -> LDS tiles ready
    bf16x8 af[4], bfr[4];
#pragma unroll
    for (int i = 0; i < 4; i++)
      af[i] = *(const bf16x8*)&As[(wr * 64 + i * 16 + lr) * 32 + lg * 8];
#pragma unroll
    for (int i = 0; i < 4; i++)
      bfr[i] = *(const bf16x8*)&Bs[(wc * 64 + i * 16 + lr) * 32 + lg * 8];
#pragma unroll
    for (int mi = 0; mi < 4; mi++)
#pragma unroll
      for (int ni = 0; ni < 4; ni++)
        acc[mi][ni] = __builtin_amdgcn_mfma_f32_16x16x32_bf16(
            af[mi], bfr[ni], acc[mi][ni], 0, 0, 0);
    __syncthreads();  // all reads done before next stage overwrites
  }

#pragma unroll
  for (int mi = 0; mi < 4; mi++) {
#pragma unroll
    for (int ni = 0; ni < 4; ni++) {
      int col = n0 + wc * 64 + ni * 16 + lr;
      float bv = bias[col];
#pragma unroll
      for (int r = 0; r < 4; r++) {
        int row = m0 + wr * 64 + mi * 16 + lg * 4 + r;
        float v = (acc[mi][ni][r] + bv) * scale;
        if (OUT_F32) Cf[(size_t)row * N + col] = v;
        else         Cb[(size_t)row * N + col] = (bf16)v;
      }
    }
  }
}

// ---------------- flash attention: per (b,h) x 64-row q-block ----------------
// Q/K/V stored [B*S, D] bf16; head h = cols h*64..h*64+63. Q pre-scaled by QSCALE.
__global__ __launch_bounds__(256, 2)
void attn_kernel(const bf16* __restrict__ Qp, const bf16* __restrict__ Kp,
                 const bf16* __restrict__ Vp, bf16* __restrict__ Oc) {
  __shared__ bf16 Ks[64][72];       // [kv][dk], row pad 72 (144B = 9*16B)
  __shared__ bf16 Vt[64][72];       // [dk][kv] transposed
  __shared__ bf16 Ps[4][16][72];    // per-wave P tile [qrow][kv]

  const int t = threadIdx.x, w = t >> 6, l = t & 63;
  const int lr = l & 15, lg = l >> 4;
  const int bh = blockIdx.y;             // b*NH + h
  const int b = bh >> 4, h = bh & 15;
  const int q0 = blockIdx.x * 64;
  const size_t base = (size_t)b * S * D + (size_t)h * 64;

  // Q fragments in registers: rows q0 + w*16 + lr, k = ks*32 + lg*8
  bf16x8 qf[2];
  {
    const bf16* qrow = Qp + base + (size_t)(q0 + w * 16 + lr) * D;
    qf[0] = *(const bf16x8*)(qrow + lg * 8);
    qf[1] = *(const bf16x8*)(qrow + 32 + lg * 8);
  }

  f32x4 accO[4] = {};
  float mrun[4], lrun[4];
#pragma unroll
  for (int r = 0; r < 4; r++) { mrun[r] = -1e30f; lrun[r] = 0.f; }

  const int srow = t >> 2, seg = t & 3;  // staging: kv-row, 16-col segment
  const bf16* Kg = Kp + base + (size_t)srow * D + seg * 16;
  const bf16* Vg = Vp + base + (size_t)srow * D + seg * 16;

  for (int kv0 = 0; kv0 < S; kv0 += 64) {
    bf16x8 k0v = *(const bf16x8*)(Kg + (size_t)kv0 * D);
    bf16x8 k1v = *(const bf16x8*)(Kg + (size_t)kv0 * D + 8);
    bf16x8 v0v = *(const bf16x8*)(Vg + (size_t)kv0 * D);
    bf16x8 v1v = *(const bf16x8*)(Vg + (size_t)kv0 * D + 8);
    *(bf16x8*)&Ks[srow][seg * 16] = k0v;
    *(bf16x8*)&Ks[srow][seg * 16 + 8] = k1v;
#pragma unroll
    for (int j = 0; j < 8; j++) Vt[seg * 16 + j][srow] = v0v[j];
#pragma unroll
    for (int j = 0; j < 8; j++) Vt[seg * 16 + 8 + j][srow] = v1v[j];
    __syncthreads();

    // QK^T : scores tile 16(q) x 64(kv) per wave
    f32x4 sc[4] = {};
#pragma unroll
    for (int ks = 0; ks < 2; ks++)
#pragma unroll
      for (int n = 0; n < 4; n++) {
        bf16x8 kf = *(const bf16x8*)&Ks[n * 16 + lr][ks * 32 + lg * 8];
        sc[n] = __builtin_amdgcn_mfma_f32_16x16x32_bf16(qf[ks], kf, sc[n], 0, 0, 0);
      }

    // online softmax (exp2 domain; scale folded into Q)
    float al[4], ps[4];
#pragma unroll
    for (int r = 0; r < 4; r++) {
      float m = fmaxf(fmaxf(sc[0][r], sc[1][r]), fmaxf(sc[2][r], sc[3][r]));
#pragma unroll
      for (int msk = 1; msk < 16; msk <<= 1)
        m = fmaxf(m, __shfl_xor(m, msk, 64));
      float mn = fmaxf(mrun[r], m);
      al[r] = exp2f(mrun[r] - mn);
      mrun[r] = mn;
      ps[r] = 0.f;
    }
#pragma unroll
    for (int n = 0; n < 4; n++)
#pragma unroll
      for (int r = 0; r < 4; r++) {
        float p = exp2f(sc[n][r] - mrun[r]);
        ps[r] += p;
        Ps[w][lg * 4 + r][n * 16 + lr] = (bf16)p;
      }
#pragma unroll
    for (int r = 0; r < 4; r++) {
      float s = ps[r];
#pragma unroll
      for (int msk = 1; msk < 16; msk <<= 1) s += __shfl_xor(s, msk, 64);
      lrun[r] = lrun[r] * al[r] + s;
#pragma unroll
      for (int n = 0; n < 4; n++) accO[n][r] *= al[r];
    }

    // PV : accO += P @ V  (B-operand from transposed Vt)
#pragma unroll
    for (int ks = 0; ks < 2; ks++) {
      bf16x8 pa = *(const bf16x8*)&Ps[w][lr][ks * 32 + lg * 8];
#pragma unroll
      for (int n = 0; n < 4; n++) {
        bf16x8 vf = *(const bf16x8*)&Vt[n * 16 + lr][ks * 32 + lg * 8];
        accO[n] = __builtin_amdgcn_mfma_f32_16x16x32_bf16(pa, vf, accO[n], 0, 0, 0);
      }
    }
    __syncthreads();
  }

#pragma unroll
  for (int n = 0; n < 4; n++)
#pragma unroll
    for (int r = 0; r < 4; r++) {
      float v = accO[n][r] / lrun[r];
      int row = q0 + w * 16 + lg * 4 + r;
      Oc[base + (size_t)row * D + n * 16 + lr] = (bf16)v;
    }
}

// ---------------- host ----------------
extern "C" void kernel_launch(void* const* d_in, const int* in_sizes, int n_in,
                              void* d_out, int out_size, void* d_ws, size_t ws_size,
                              hipStream_t stream) {
  const float* q  = (const float*)d_in[0];
  const float* k  = (const float*)d_in[1];
  const float* v  = (const float*)d_in[2];
  const float* Wq = (const float*)d_in[3];
  const float* bq = (const float*)d_in[4];
  const float* Wk = (const float*)d_in[5];
  const float* bk = (const float*)d_in[6];
  const float* Wv = (const float*)d_in[7];
  const float* bv = (const float*)d_in[8];
  const float* Wo = (const float*)d_in[9];
  const float* bo = (const float*)d_in[10];
  float* out = (float*)d_out;

  const int BS = 2 * S;                      // 4096 rows
  const size_t SZ_T = (size_t)BS * D * 2;    // 8 MB per [B*S,D] bf16 tensor
  const size_t SZ_W = (size_t)D * D * 2;     // 2 MB per weight bf16

  char* ws = (char*)d_ws;
  bf16* qb  = (bf16*)(ws);
  bf16* kb  = (bf16*)(ws + SZ_T);
  bf16* vb  = (bf16*)(ws + 2 * SZ_T);
  bf16* Wqb = (bf16*)(ws + 3 * SZ_T);
  bf16* Wkb = (bf16*)(ws + 3 * SZ_T + SZ_W);
  bf16* Wvb = (bf16*)(ws + 3 * SZ_T + 2 * SZ_W);
  bf16* Wob = (bf16*)(ws + 3 * SZ_T + 3 * SZ_W);
  bf16* Qh  = (bf16*)(ws + 3 * SZ_T + 4 * SZ_W);
  bf16* Kh  = (bf16*)(ws + 4 * SZ_T + 4 * SZ_W);
  bf16* Vh  = (bf16*)(ws + 5 * SZ_T + 4 * SZ_W);
  bf16* Oc  = qb;  // reuse: qb dead after Q projection; attn runs later

  const int n8t = BS * D / 8;   // 524288
  const int n8w = D * D / 8;    // 131072
  cvt_kernel<<<dim3((n8t + 255) / 256), 256, 0, stream>>>(q, qb, n8t);
  cvt_kernel<<<dim3((n8t + 255) / 256), 256, 0, stream>>>(k, kb, n8t);
  cvt_kernel<<<dim3((n8t + 255) / 256), 256, 0, stream>>>(v, vb, n8t);
  cvt_kernel<<<dim3((n8w + 255) / 256), 256, 0, stream>>>(Wq, Wqb, n8w);
  cvt_kernel<<<dim3((n8w + 255) / 256), 256, 0, stream>>>(Wk, Wkb, n8w);
  cvt_kernel<<<dim3((n8w + 255) / 256), 256, 0, stream>>>(Wv, Wvb, n8w);
  cvt_kernel<<<dim3((n8w + 255) / 256), 256, 0, stream>>>(Wo, Wob, n8w);

  dim3 gg(D / 128, BS / 128);  // (8, 32)
  gemm_bt<false><<<gg, 256, 0, stream>>>(qb, Wqb, bq, Qh, nullptr, BS, D, D, QSCALE);
  gemm_bt<false><<<gg, 256, 0, stream>>>(kb, Wkb, bk, Kh, nullptr, BS, D, D, 1.0f);
  gemm_bt<false><<<gg, 256, 0, stream>>>(vb, Wvb, bv, Vh, nullptr, BS, D, D, 1.0f);

  attn_kernel<<<dim3(S / 64, 2 * NH), 256, 0, stream>>>(Qh, Kh, Vh, Oc);

  gemm_bt<true><<<gg, 256, 0, stream>>>(Oc, Wob, bo, nullptr, out, BS, D, D, 1.0f);
}

// Round 3
// 259.596 us; speedup vs baseline: 1.4528x; 1.4528x over previous
//
#include <hip/hip_runtime.h>
#include <stdint.h>

#define DEV __device__ __forceinline__

typedef __bf16 bf16;
typedef __bf16 bf16x8 __attribute__((ext_vector_type(8)));
typedef unsigned short u16x8 __attribute__((ext_vector_type(8)));
typedef float f32x4 __attribute__((ext_vector_type(4)));
typedef uint32_t u32x4 __attribute__((ext_vector_type(4)));

static constexpr int S = 2048, D = 1024, NH = 16;
// fold 1/sqrt(DK) * log2(e) into Q so softmax runs in exp2 domain
static constexpr float QSCALE = 0.125f * 1.44269504088896340736f;

union BU { u16x8 u; bf16x8 v; };
union PU { u32x4 u; bf16x8 v; };

DEV uint32_t pack2(float a, float b) {
  union { __bf16 h; uint16_t u; } x, y;
  x.h = (__bf16)a; y.h = (__bf16)b;
  return (uint32_t)x.u | ((uint32_t)y.u << 16);
}

// ---------------- batched f32 -> bf16 convert (7 segments, 1 launch) --------
struct CvtArgs { const float* s[7]; bf16* d[7]; };
// blocks: 3 x 2048 (activations) then 4 x 512 (weights)
__global__ __launch_bounds__(256) void cvt_all(CvtArgs a) {
  int blk = blockIdx.x, seg, rel;
  if (blk < 6144) { seg = blk >> 11; rel = blk & 2047; }
  else { int bb = blk - 6144; seg = 3 + (bb >> 9); rel = bb & 511; }
  int i = rel * 256 + threadIdx.x;
  const float4* p = (const float4*)a.s[seg] + (size_t)i * 2;
  float4 x = p[0], y = p[1];
  bf16x8 o;
  o[0] = (bf16)x.x; o[1] = (bf16)x.y; o[2] = (bf16)x.z; o[3] = (bf16)x.w;
  o[4] = (bf16)y.x; o[5] = (bf16)y.y; o[6] = (bf16)y.z; o[7] = (bf16)y.w;
  ((bf16x8*)a.d[seg])[i] = o;
}

// ---------------- async global->LDS 16B ----------------
DEV void async_copy16(bf16* lds_dst, const bf16* g_src) {
  __builtin_amdgcn_global_load_lds(
      (const __attribute__((address_space(1))) void*)(g_src),
      (__attribute__((address_space(3))) void*)(lds_dst),
      16, 0, 0);
}

// ---------------- C = A * W^T + bias, all GEMMs are 4096x1024x1024 ----------
struct GArgs {
  const bf16* A[3]; const bf16* W[3]; const float* bias[3];
  bf16* Cb[3]; float* Cf[3]; float scale[3];
};

template <bool OUT_F32>
__global__ __launch_bounds__(256, 2)
void gemm_multi(GArgs g) {
  constexpr int N = 1024, K = 1024;
  const int z = blockIdx.z;
  const bf16* A = g.A[z];
  const bf16* Bt = g.W[z];
  const float* bias = g.bias[z];
  const float scale = g.scale[z];

  __shared__ bf16 As[128 * 32];
  __shared__ bf16 Bs[128 * 32];
  const int t = threadIdx.x;
  const int w = t >> 6, l = t & 63;
  const int wr = w >> 1, wc = w & 1;
  const int lr = l & 15, lg = l >> 4;
  const int m0 = blockIdx.y * 128, n0 = blockIdx.x * 128;

  f32x4 acc[4][4] = {};

  const int srow = t >> 2, scol = (t & 3) * 8;
  const bf16* Aptr = A + (size_t)(m0 + srow) * K + scol;
  const bf16* Bptr = Bt + (size_t)(n0 + srow) * K + scol;
  bf16* AsDst = &As[w * 512];
  bf16* BsDst = &Bs[w * 512];

  for (int k0 = 0; k0 < K; k0 += 32) {
    async_copy16(AsDst,        Aptr + k0);
    async_copy16(AsDst + 2048, Aptr + (size_t)64 * K + k0);
    async_copy16(BsDst,        Bptr + k0);
    async_copy16(BsDst + 2048, Bptr + (size_t)64 * K + k0);
    __syncthreads();
    bf16x8 af[4], bfr[4];
#pragma unroll
    for (int i = 0; i < 4; i++)
      af[i] = *(const bf16x8*)&As[(wr * 64 + i * 16 + lr) * 32 + lg * 8];
#pragma unroll
    for (int i = 0; i < 4; i++)
      bfr[i] = *(const bf16x8*)&Bs[(wc * 64 + i * 16 + lr) * 32 + lg * 8];
#pragma unroll
    for (int mi = 0; mi < 4; mi++)
#pragma unroll
      for (int ni = 0; ni < 4; ni++)
        acc[mi][ni] = __builtin_amdgcn_mfma_f32_16x16x32_bf16(
            af[mi], bfr[ni], acc[mi][ni], 0, 0, 0);
    __syncthreads();
  }

#pragma unroll
  for (int mi = 0; mi < 4; mi++) {
#pragma unroll
    for (int ni = 0; ni < 4; ni++) {
      int col = n0 + wc * 64 + ni * 16 + lr;
      float bv = bias[col];
#pragma unroll
      for (int r = 0; r < 4; r++) {
        int row = m0 + wr * 64 + mi * 16 + lg * 4 + r;
        float v = (acc[mi][ni][r] + bv) * scale;
        if (OUT_F32) g.Cf[z][(size_t)row * N + col] = v;
        else         g.Cb[z][(size_t)row * N + col] = (bf16)v;
      }
    }
  }
}

// ---------------- flash attention, swapped-operand, in-register softmax -----
// Block: 128 q rows (4 waves x 32), KV tile 64, DK=64.
// QK^T computed as mfma(K, Q) -> P^T: each lane owns q-col (lr), 16 kv in regs.
// K LDS rows permuted so P fragment == PV A-operand with NO cross-lane repack.
// K and Vt tiles XOR-swizzled (byte ^= (row&7)<<4) -> bank-conflict floor.
__global__ __launch_bounds__(256, 2)
void attn_kernel(const bf16* __restrict__ Qp, const bf16* __restrict__ Kp,
                 const bf16* __restrict__ Vp, bf16* __restrict__ Oc) {
  __shared__ uint4 ldsu[1024];  // 16 KB: K tile [0,8K), V^T tile [8K,16K)
  char* lds = (char*)ldsu;

  const int t = threadIdx.x, w = t >> 6, l = t & 63;
  const int lr = l & 15, lg = l >> 4;
  const int bh = blockIdx.y, b = bh >> 4, h = bh & 15;
  const int q0 = blockIdx.x * 128;
  const size_t base = (size_t)b * S * D + (size_t)h * 64;

  // Q fragments (B-operand): q row = q0 + w*32 + qs*16 + lr
  bf16x8 qf[2][2];
  {
    const bf16* qb = Qp + base + (size_t)(q0 + w * 32 + lr) * D + lg * 8;
#pragma unroll
    for (int qs = 0; qs < 2; qs++)
#pragma unroll
      for (int ks = 0; ks < 2; ks++)
        qf[qs][ks] = *(const bf16x8*)(qb + (size_t)qs * 16 * D + ks * 32);
  }

  f32x4 accO[2][4] = {};
  float mrun[2] = {-3e38f, -3e38f}, lrun[2] = {0.f, 0.f};

  // K staging: thread -> global row srow, 32B segment seg.
  // LDS row rho = perm^-1(srow): bit shuffle so that the lane holding
  // P^T[m][r] (C row = m*16+lg*4+r) holds kv = 32*(m&1) + 8*lg + 4*(m>>1) + r,
  // i.e. exactly the kv the PV A-fragment needs at position k = lg*8+j.
  const int srow = t >> 2, seg = t & 3;
  const int mm = (((srow >> 2) & 1) << 1) | (srow >> 5);
  const int rho = (mm << 4) | (((srow >> 3) & 3) << 2) | (srow & 3);
  const int kswz = (rho & 7) << 4;
  const int ka0 = (rho * 128 + seg * 32) ^ kswz;
  const int ka1 = (rho * 128 + seg * 32 + 16) ^ kswz;
  // V staging: kv pair (2u, 2u+1), d columns c*8..c*8+7; packed dword writes.
  const int vu = t & 31, vc = t >> 5;
  const bf16* Kg = Kp + base + (size_t)srow * D + seg * 16;
  const bf16* Vg = Vp + base + (size_t)(2 * vu) * D + vc * 8;

  u16x8 k0 = *(const u16x8*)(Kg);
  u16x8 k1 = *(const u16x8*)(Kg + 8);
  u16x8 v0 = *(const u16x8*)(Vg);
  u16x8 v1 = *(const u16x8*)(Vg + D);

  const int rswz = (lr & 7) << 4;

  for (int kv0 = 0; kv0 < S; kv0 += 64) {
    __syncthreads();  // previous tile's reads complete
    *(u16x8*)(lds + ka0) = k0;
    *(u16x8*)(lds + ka1) = k1;
#pragma unroll
    for (int j = 0; j < 8; j++) {
      uint32_t dw = (uint32_t)v0[j] | ((uint32_t)v1[j] << 16);
      int va = 8192 + ((((vc * 8 + j) * 128) + vu * 4) ^ (j << 4));
      *(uint32_t*)(lds + va) = dw;
    }
    __syncthreads();  // tile published
    if (kv0 + 64 < S) {  // prefetch next tile under compute
      size_t off = (size_t)(kv0 + 64) * D;
      k0 = *(const u16x8*)(Kg + off);
      k1 = *(const u16x8*)(Kg + off + 8);
      v0 = *(const u16x8*)(Vg + off);
      v1 = *(const u16x8*)(Vg + off + D);
    }

    // ---- QK^T (swapped): sc[qs][m] rows = kv (permuted), cols = q
    f32x4 sc[2][4] = {};
#pragma unroll
    for (int ks = 0; ks < 2; ks++) {
      BU kf[4];
#pragma unroll
      for (int m = 0; m < 4; m++)
        kf[m].u = *(const u16x8*)(lds + ((((m * 16 + lr) * 128) + ks * 64 + lg * 16) ^ rswz));
      __builtin_amdgcn_s_setprio(1);
#pragma unroll
      for (int m = 0; m < 4; m++)
#pragma unroll
        for (int qs = 0; qs < 2; qs++)
          sc[qs][m] = __builtin_amdgcn_mfma_f32_16x16x32_bf16(
              kf[m].v, qf[qs][ks], sc[qs][m], 0, 0, 0);
      __builtin_amdgcn_s_setprio(0);
    }

    // ---- online softmax: lane owns q = qs*16+lr; 16 kv in regs, x4 lanes (lg)
    uint32_t pk[2][4][2];
    float alq[2];
#pragma unroll
    for (int qs = 0; qs < 2; qs++) {
      float mx = sc[qs][0][0];
#pragma unroll
      for (int m = 0; m < 4; m++)
#pragma unroll
        for (int r = 0; r < 4; r++) mx = fmaxf(mx, sc[qs][m][r]);
      mx = fmaxf(mx, __shfl_xor(mx, 16));
      mx = fmaxf(mx, __shfl_xor(mx, 32));
      float mn = fmaxf(mrun[qs], mx);
      float al = exp2f(mrun[qs] - mn);
      mrun[qs] = mn;
      float s = 0.f;
#pragma unroll
      for (int m = 0; m < 4; m++) {
        float p0 = exp2f(sc[qs][m][0] - mn);
        float p1 = exp2f(sc[qs][m][1] - mn);
        float p2 = exp2f(sc[qs][m][2] - mn);
        float p3 = exp2f(sc[qs][m][3] - mn);
        s += (p0 + p1) + (p2 + p3);
        pk[qs][m][0] = pack2(p0, p1);
        pk[qs][m][1] = pack2(p2, p3);
      }
      s += __shfl_xor(s, 16);
      s += __shfl_xor(s, 32);
      lrun[qs] = lrun[qs] * al + s;
      alq[qs] = al;
    }
    // redistribute al (stats live at q=lr; accO rows live at q=lg*4+r)
#pragma unroll
    for (int qs = 0; qs < 2; qs++)
#pragma unroll
      for (int r = 0; r < 4; r++) {
        float a = __shfl(alq[qs], (lg << 4) | (lg * 4 + r));
#pragma unroll
        for (int n = 0; n < 4; n++) accO[qs][n][r] *= a;
      }

    // ---- PV: A = P (lane-local thanks to K-row permutation), B^T = V^T tile
#pragma unroll
    for (int ks = 0; ks < 2; ks++) {
      PU pa[2];
#pragma unroll
      for (int qs = 0; qs < 2; qs++) {
        pa[qs].u[0] = pk[qs][ks][0];
        pa[qs].u[1] = pk[qs][ks][1];
        pa[qs].u[2] = pk[qs][2 + ks][0];
        pa[qs].u[3] = pk[qs][2 + ks][1];
      }
      BU vf[4];
#pragma unroll
      for (int n = 0; n < 4; n++)
        vf[n].u = *(const u16x8*)(lds + 8192 +
                   ((((n * 16 + lr) * 128) + ks * 64 + lg * 16) ^ rswz));
      __builtin_amdgcn_s_setprio(1);
#pragma unroll
      for (int n = 0; n < 4; n++)
#pragma unroll
        for (int qs = 0; qs < 2; qs++)
          accO[qs][n] = __builtin_amdgcn_mfma_f32_16x16x32_bf16(
              pa[qs].v, vf[n].v, accO[qs][n], 0, 0, 0);
      __builtin_amdgcn_s_setprio(0);
    }
  }

  // ---- epilogue: divide by redistributed row-sum, store
#pragma unroll
  for (int qs = 0; qs < 2; qs++)
#pragma unroll
    for (int r = 0; r < 4; r++) {
      float lv = __shfl(lrun[qs], (lg << 4) | (lg * 4 + r));
      float rl = 1.0f / lv;
      int row = q0 + w * 32 + qs * 16 + lg * 4 + r;
      bf16* orow = Oc + base + (size_t)row * D;
#pragma unroll
      for (int n = 0; n < 4; n++) orow[n * 16 + lr] = (bf16)(accO[qs][n][r] * rl);
    }
}

// ---------------- host ----------------
extern "C" void kernel_launch(void* const* d_in, const int* in_sizes, int n_in,
                              void* d_out, int out_size, void* d_ws, size_t ws_size,
                              hipStream_t stream) {
  const float* q  = (const float*)d_in[0];
  const float* k  = (const float*)d_in[1];
  const float* v  = (const float*)d_in[2];
  const float* Wq = (const float*)d_in[3];
  const float* bq = (const float*)d_in[4];
  const float* Wk = (const float*)d_in[5];
  const float* bk = (const float*)d_in[6];
  const float* Wv = (const float*)d_in[7];
  const float* bv = (const float*)d_in[8];
  const float* Wo = (const float*)d_in[9];
  const float* bo = (const float*)d_in[10];
  float* out = (float*)d_out;

  const int BS = 2 * S;                      // 4096 rows
  const size_t SZ_T = (size_t)BS * D * 2;    // 8 MB
  const size_t SZ_W = (size_t)D * D * 2;     // 2 MB

  char* ws = (char*)d_ws;
  bf16* qb  = (bf16*)(ws);
  bf16* kb  = (bf16*)(ws + SZ_T);
  bf16* vb  = (bf16*)(ws + 2 * SZ_T);
  bf16* Wqb = (bf16*)(ws + 3 * SZ_T);
  bf16* Wkb = (bf16*)(ws + 3 * SZ_T + SZ_W);
  bf16* Wvb = (bf16*)(ws + 3 * SZ_T + 2 * SZ_W);
  bf16* Wob = (bf16*)(ws + 3 * SZ_T + 3 * SZ_W);
  bf16* Qh  = (bf16*)(ws + 3 * SZ_T + 4 * SZ_W);
  bf16* Kh  = (bf16*)(ws + 4 * SZ_T + 4 * SZ_W);
  bf16* Vh  = (bf16*)(ws + 5 * SZ_T + 4 * SZ_W);
  bf16* Oc  = qb;  // qb dead after projections

  CvtArgs ca;
  ca.s[0] = q;  ca.d[0] = qb;
  ca.s[1] = k;  ca.d[1] = kb;
  ca.s[2] = v;  ca.d[2] = vb;
  ca.s[3] = Wq; ca.d[3] = Wqb;
  ca.s[4] = Wk; ca.d[4] = Wkb;
  ca.s[5] = Wv; ca.d[5] = Wvb;
  ca.s[6] = Wo; ca.d[6] = Wob;
  cvt_all<<<dim3(8192), 256, 0, stream>>>(ca);

  GArgs gp = {};
  gp.A[0] = qb; gp.W[0] = Wqb; gp.bias[0] = bq; gp.Cb[0] = Qh; gp.scale[0] = QSCALE;
  gp.A[1] = kb; gp.W[1] = Wkb; gp.bias[1] = bk; gp.Cb[1] = Kh; gp.scale[1] = 1.0f;
  gp.A[2] = vb; gp.W[2] = Wvb; gp.bias[2] = bv; gp.Cb[2] = Vh; gp.scale[2] = 1.0f;
  gemm_multi<false><<<dim3(D / 128, BS / 128, 3), 256, 0, stream>>>(gp);

  attn_kernel<<<dim3(S / 128, 2 * NH), 256, 0, stream>>>(Qh, Kh, Vh, Oc);

  GArgs go = {};
  go.A[0] = Oc; go.W[0] = Wob; go.bias[0] = bo; go.Cf[0] = out; go.scale[0] = 1.0f;
  gemm_multi<true><<<dim3(D / 128, BS / 128, 1), 256, 0, stream>>>(go);
}

// Round 5
// 253.541 us; speedup vs baseline: 1.4875x; 1.0239x over previous
//
#include <hip/hip_runtime.h>
#include <stdint.h>

#define DEV __device__ __forceinline__

typedef __bf16 bf16;
typedef __bf16 bf16x8 __attribute__((ext_vector_type(8)));
typedef unsigned short u16x8 __attribute__((ext_vector_type(8)));
typedef float f32x4 __attribute__((ext_vector_type(4)));
typedef uint32_t u32x4 __attribute__((ext_vector_type(4)));

static constexpr int S = 2048, D = 1024, NH = 16;
// fold 1/sqrt(DK) * log2(e) into Q so softmax runs in exp2 domain
static constexpr float QSCALE = 0.125f * 1.44269504088896340736f;
static constexpr float DTHR = 8.0f;  // defer-max threshold (exp2 domain)

union BU { u16x8 u; bf16x8 v; };
union PU { u32x4 u; bf16x8 v; };

DEV uint32_t pack2(float a, float b) {
  union { __bf16 h; uint16_t u; } x, y;
  x.h = (__bf16)a; y.h = (__bf16)b;
  return (uint32_t)x.u | ((uint32_t)y.u << 16);
}

// ---------------- batched f32 -> bf16 convert (7 segments, 1 launch) --------
struct CvtArgs { const float* s[7]; bf16* d[7]; };
__global__ __launch_bounds__(256) void cvt_all(CvtArgs a) {
  int blk = blockIdx.x, seg, rel;
  if (blk < 6144) { seg = blk >> 11; rel = blk & 2047; }
  else { int bb = blk - 6144; seg = 3 + (bb >> 9); rel = bb & 511; }
  int i = rel * 256 + threadIdx.x;
  const float4* p = (const float4*)a.s[seg] + (size_t)i * 2;
  float4 x = p[0], y = p[1];
  bf16x8 o;
  o[0] = (bf16)x.x; o[1] = (bf16)x.y; o[2] = (bf16)x.z; o[3] = (bf16)x.w;
  o[4] = (bf16)y.x; o[5] = (bf16)y.y; o[6] = (bf16)y.z; o[7] = (bf16)y.w;
  ((bf16x8*)a.d[seg])[i] = o;
}

// ---------------- async global->LDS 16B ----------------
DEV void async_copy16(bf16* lds_dst, const bf16* g_src) {
  __builtin_amdgcn_global_load_lds(
      (const __attribute__((address_space(1))) void*)(g_src),
      (__attribute__((address_space(3))) void*)(lds_dst),
      16, 0, 0);
}

// ---------------- C = A * W^T + bias  (BM=128, BN=64, BK=32) ----------------
struct GArgs {
  const bf16* A[3]; const bf16* W[3]; const float* bias[3];
  bf16* Cb[3]; float* Cf[3]; float scale[3];
};

template <bool OUT_F32>
__global__ __launch_bounds__(256, 2)
void gemm_multi(GArgs g) {
  constexpr int N = 1024, K = 1024;
  const int z = blockIdx.z;
  const bf16* A = g.A[z];
  const bf16* Bt = g.W[z];
  const float* bias = g.bias[z];
  const float scale = g.scale[z];

  __shared__ bf16 As[128 * 32];  // 8 KB
  __shared__ bf16 Bs[64 * 32];   // 4 KB
  const int t = threadIdx.x;
  const int w = t >> 6, l = t & 63;
  const int lr = l & 15, lg = l >> 4;
  const int m0 = blockIdx.y * 128, n0 = blockIdx.x * 64;

  f32x4 acc[2][4] = {};

  const int srow = t >> 2, scol = (t & 3) * 8;
  const bf16* Aptr = A + (size_t)(m0 + srow) * K + scol;
  const bf16* Bptr = Bt + (size_t)(n0 + srow) * K + scol;
  bf16* AsDst = &As[w * 512];   // wave-uniform; HW adds lane*16B
  bf16* BsDst = &Bs[w * 512];

  for (int k0 = 0; k0 < K; k0 += 32) {
    async_copy16(AsDst,        Aptr + k0);                    // A rows 0..63
    async_copy16(AsDst + 2048, Aptr + (size_t)64 * K + k0);   // A rows 64..127
    async_copy16(BsDst,        Bptr + k0);                    // B rows 0..63
    __syncthreads();
    bf16x8 af[2], bfr[4];
#pragma unroll
    for (int i = 0; i < 2; i++)
      af[i] = *(const bf16x8*)&As[(w * 32 + i * 16 + lr) * 32 + lg * 8];
#pragma unroll
    for (int n = 0; n < 4; n++)
      bfr[n] = *(const bf16x8*)&Bs[(n * 16 + lr) * 32 + lg * 8];
#pragma unroll
    for (int mi = 0; mi < 2; mi++)
#pragma unroll
      for (int ni = 0; ni < 4; ni++)
        acc[mi][ni] = __builtin_amdgcn_mfma_f32_16x16x32_bf16(
            af[mi], bfr[ni], acc[mi][ni], 0, 0, 0);
    __syncthreads();
  }

#pragma unroll
  for (int mi = 0; mi < 2; mi++) {
#pragma unroll
    for (int ni = 0; ni < 4; ni++) {
      int col = n0 + ni * 16 + lr;
      float bv = bias[col];
#pragma unroll
      for (int r = 0; r < 4; r++) {
        int row = m0 + w * 32 + mi * 16 + lg * 4 + r;
        float v = (acc[mi][ni][r] + bv) * scale;
        if (OUT_F32) g.Cf[z][(size_t)row * N + col] = v;
        else         g.Cb[z][(size_t)row * N + col] = (bf16)v;
      }
    }
  }
}

// ---------------- flash attention ----------------
// 128 q rows / block (4 waves x 32), KV tile 64, DK=64.
// K staged by global_load_lds with permuted+swizzled SOURCE addressing (LDS
// linear, zero staging VGPRs); K,V LDS double-buffered; ONE barrier per tile.
// Swapped QK^T (mfma(K,Q)) -> P lane-local; defer-max so the common softmax
// path has NO cross-lane ops; row-sums kept as per-lane partials to epilogue.
__global__ __launch_bounds__(256, 2)
void attn_kernel(const bf16* __restrict__ Qp, const bf16* __restrict__ Kp,
                 const bf16* __restrict__ Vp, bf16* __restrict__ Oc) {
  __shared__ uint4 ldsu[2048];  // 32 KB: K dbuf [0,16K), V^T dbuf [16K,32K)
  char* lds = (char*)ldsu;

  const int t = threadIdx.x, w = t >> 6, l = t & 63;
  const int lr = l & 15, lg = l >> 4;
  const int bh = blockIdx.y, b = bh >> 4, h = bh & 15;
  const int q0 = blockIdx.x * 128;
  const size_t base = (size_t)b * S * D + (size_t)h * 64;
  const size_t TILE = (size_t)64 * D;

  // Q fragments (B-operand): q row = q0 + w*32 + qs*16 + lr
  bf16x8 qf[2][2];
  {
    const bf16* qb = Qp + base + (size_t)(q0 + w * 32 + lr) * D + lg * 8;
#pragma unroll
    for (int qs = 0; qs < 2; qs++)
#pragma unroll
      for (int ks = 0; ks < 2; ks++)
        qf[qs][ks] = *(const bf16x8*)(qb + (size_t)qs * 16 * D + ks * 32);
  }

  f32x4 accO[2][4] = {};
  float mrun[2] = {-1e30f, -1e30f}, lsum[2] = {0.f, 0.f};

  // --- K source addressing for global_load_lds (LDS linear dest) ---
  // LDS byte o = w*2048 + c*1024 + lane*16 must hold K[srow][seg16*8..+7]
  // where rho=o>>7, seg16=((o&127)^((rho&7)<<4))>>4, srow=perm(rho).
  const bf16* kptr[2];
#pragma unroll
  for (int c = 0; c < 2; c++) {
    int o = w * 2048 + c * 1024 + l * 16;
    int rho = o >> 7;
    int seg16 = ((o & 127) ^ ((rho & 7) << 4)) >> 4;
    int mm = rho >> 4;
    int srow = ((mm & 1) << 5) | (((rho >> 2) & 3) << 3) | ((mm >> 1) << 2) | (rho & 3);
    kptr[c] = Kp + base + (size_t)srow * D + seg16 * 8;
  }

  // --- V staging (reg transpose -> packed dword writes, swizzled) ---
  const int vu = t & 31, vc = t >> 5;
  const bf16* Vg = Vp + base + (size_t)(2 * vu) * D + vc * 8;
  int vwa[8];
#pragma unroll
  for (int j = 0; j < 8; j++)
    vwa[j] = 16384 + (((vc * 8 + j) * 128 + vu * 4) ^ (j << 4));

  const int rswz = (lr & 7) << 4;

  // ---- prologue: K(0) -> Kbuf0 (async); V(0) -> regs
  async_copy16((bf16*)(lds + w * 2048),        kptr[0]);
  async_copy16((bf16*)(lds + w * 2048 + 1024), kptr[1]);
  u16x8 va = *(const u16x8*)(Vg);
  u16x8 vb = *(const u16x8*)(Vg + D);
  __syncthreads();  // K(0) + V(0) loads complete
  {
#pragma unroll
    for (int j = 0; j < 8; j++) {
      uint32_t dw = (uint32_t)va[j] | ((uint32_t)vb[j] << 16);
      *(uint32_t*)(lds + vwa[j]) = dw;
    }
  }
  va = *(const u16x8*)(Vg + TILE);
  vb = *(const u16x8*)(Vg + TILE + D);
  __syncthreads();  // Vt(0) published

  const bf16* kp0 = kptr[0] + TILE;
  const bf16* kp1 = kptr[1] + TILE;
  const bf16* vg2 = Vg + 2 * TILE;

  for (int it = 0; it < 32; ++it) {
    const int cur = (it & 1) * 8192;
    const int nxt = ((it + 1) & 1) * 8192;
    const bool hasN = it < 31, hasN2 = it < 30;

    // issue next K tile copies (async, zero VGPR)
    if (hasN) {
      async_copy16((bf16*)(lds + nxt + w * 2048),        kp0);
      async_copy16((bf16*)(lds + nxt + w * 2048 + 1024), kp1);
      kp0 += TILE; kp1 += TILE;
    }
    // issue V(it+2) loads early (drained at end-of-iter barrier)
    const bf16* pv = hasN2 ? vg2 : (Vp + base);
    u16x8 ta = *(const u16x8*)(pv);
    u16x8 tb = *(const u16x8*)(pv + D);
    vg2 += TILE;

    // ---- QK^T (swapped): sc[qs][m], rows = kv (permuted), cols = q
    f32x4 sc[2][4] = {};
#pragma unroll
    for (int ks = 0; ks < 2; ks++) {
      BU kf[4];
#pragma unroll
      for (int m = 0; m < 4; m++)
        kf[m].u = *(const u16x8*)(lds + cur +
                   ((((m * 16 + lr) * 128) + ks * 64 + lg * 16) ^ rswz));
      __builtin_amdgcn_s_setprio(1);
#pragma unroll
      for (int m = 0; m < 4; m++)
#pragma unroll
        for (int qs = 0; qs < 2; qs++)
          sc[qs][m] = __builtin_amdgcn_mfma_f32_16x16x32_bf16(
              kf[m].v, qf[qs][ks], sc[qs][m], 0, 0, 0);
      __builtin_amdgcn_s_setprio(0);
    }

    // ---- softmax, defer-max: common path has ZERO cross-lane ops
    float mx[2];
#pragma unroll
    for (int qs = 0; qs < 2; qs++) {
      float a0 = fmaxf(fmaxf(sc[qs][0][0], sc[qs][0][1]), fmaxf(sc[qs][0][2], sc[qs][0][3]));
      float a1 = fmaxf(fmaxf(sc[qs][1][0], sc[qs][1][1]), fmaxf(sc[qs][1][2], sc[qs][1][3]));
      float a2 = fmaxf(fmaxf(sc[qs][2][0], sc[qs][2][1]), fmaxf(sc[qs][2][2], sc[qs][2][3]));
      float a3 = fmaxf(fmaxf(sc[qs][3][0], sc[qs][3][1]), fmaxf(sc[qs][3][2], sc[qs][3][3]));
      mx[qs] = fmaxf(fmaxf(a0, a1), fmaxf(a2, a3));
    }
    bool stable = (mx[0] <= mrun[0] + DTHR) & (mx[1] <= mrun[1] + DTHR);
    if (!__all(stable)) {
      float alq[2];
#pragma unroll
      for (int qs = 0; qs < 2; qs++) {
        float m2 = fmaxf(mx[qs], __shfl_xor(mx[qs], 16));
        m2 = fmaxf(m2, __shfl_xor(m2, 32));
        float mn = fmaxf(mrun[qs], m2);
        float al = exp2f(mrun[qs] - mn);
        mrun[qs] = mn;
        lsum[qs] *= al;
        alq[qs] = al;
      }
#pragma unroll
      for (int qs = 0; qs < 2; qs++)
#pragma unroll
        for (int r = 0; r < 4; r++) {
          float a = __shfl(alq[qs], (lg << 4) | (lg * 4 + r));
#pragma unroll
          for (int n = 0; n < 4; n++) accO[qs][n][r] *= a;
        }
    }
    uint32_t pk[2][4][2];
#pragma unroll
    for (int qs = 0; qs < 2; qs++) {
      float s = 0.f;
#pragma unroll
      for (int m = 0; m < 4; m++) {
        float p0 = exp2f(sc[qs][m][0] - mrun[qs]);
        float p1 = exp2f(sc[qs][m][1] - mrun[qs]);
        float p2 = exp2f(sc[qs][m][2] - mrun[qs]);
        float p3 = exp2f(sc[qs][m][3] - mrun[qs]);
        s += (p0 + p1) + (p2 + p3);
        pk[qs][m][0] = pack2(p0, p1);
        pk[qs][m][1] = pack2(p2, p3);
      }
      lsum[qs] += s;
    }

    // ---- publish Vt(it+1) into other buffer (read next iter)
    if (hasN) {
#pragma unroll
      for (int j = 0; j < 8; j++) {
        uint32_t dw = (uint32_t)va[j] | ((uint32_t)vb[j] << 16);
        *(uint32_t*)(lds + vwa[j] + nxt) = dw;
      }
    }

    // ---- PV: A = P (lane-local), B = V^T tile
#pragma unroll
    for (int ks = 0; ks < 2; ks++) {
      PU pa[2];
#pragma unroll
      for (int qs = 0; qs < 2; qs++) {
        pa[qs].u[0] = pk[qs][ks][0];
        pa[qs].u[1] = pk[qs][ks][1];
        pa[qs].u[2] = pk[qs][2 + ks][0];
        pa[qs].u[3] = pk[qs][2 + ks][1];
      }
      BU vf[4];
#pragma unroll
      for (int n = 0; n < 4; n++)
        vf[n].u = *(const u16x8*)(lds + 16384 + cur +
                   ((((n * 16 + lr) * 128) + ks * 64 + lg * 16) ^ rswz));
      __builtin_amdgcn_s_setprio(1);
#pragma unroll
      for (int n = 0; n < 4; n++)
#pragma unroll
        for (int qs = 0; qs < 2; qs++)
          accO[qs][n] = __builtin_amdgcn_mfma_f32_16x16x32_bf16(
              pa[qs].v, vf[n].v, accO[qs][n], 0, 0, 0);
      __builtin_amdgcn_s_setprio(0);
    }

    va = ta; vb = tb;
    __syncthreads();  // drains K copies + V-loads + Vt writes; publishes tile it+1
  }

  // ---- epilogue: reduce partial row-sums once, divide, store
#pragma unroll
  for (int qs = 0; qs < 2; qs++) {
    lsum[qs] += __shfl_xor(lsum[qs], 16);
    lsum[qs] += __shfl_xor(lsum[qs], 32);
  }
#pragma unroll
  for (int qs = 0; qs < 2; qs++)
#pragma unroll
    for (int r = 0; r < 4; r++) {
      float lv = __shfl(lsum[qs], (lg << 4) | (lg * 4 + r));
      float rl = 1.0f / lv;
      int row = q0 + w * 32 + qs * 16 + lg * 4 + r;
      bf16* orow = Oc + base + (size_t)row * D;
#pragma unroll
      for (int n = 0; n < 4; n++) orow[n * 16 + lr] = (bf16)(accO[qs][n][r] * rl);
    }
}

// ---------------- host ----------------
extern "C" void kernel_launch(void* const* d_in, const int* in_sizes, int n_in,
                              void* d_out, int out_size, void* d_ws, size_t ws_size,
                              hipStream_t stream) {
  const float* q  = (const float*)d_in[0];
  const float* k  = (const float*)d_in[1];
  const float* v  = (const float*)d_in[2];
  const float* Wq = (const float*)d_in[3];
  const float* bq = (const float*)d_in[4];
  const float* Wk = (const float*)d_in[5];
  const float* bk = (const float*)d_in[6];
  const float* Wv = (const float*)d_in[7];
  const float* bv = (const float*)d_in[8];
  const float* Wo = (const float*)d_in[9];
  const float* bo = (const float*)d_in[10];
  float* out = (float*)d_out;

  const int BS = 2 * S;                      // 4096 rows
  const size_t SZ_T = (size_t)BS * D * 2;    // 8 MB
  const size_t SZ_W = (size_t)D * D * 2;     // 2 MB

  char* ws = (char*)d_ws;
  bf16* qb  = (bf16*)(ws);
  bf16* kb  = (bf16*)(ws + SZ_T);
  bf16* vb  = (bf16*)(ws + 2 * SZ_T);
  bf16* Wqb = (bf16*)(ws + 3 * SZ_T);
  bf16* Wkb = (bf16*)(ws + 3 * SZ_T + SZ_W);
  bf16* Wvb = (bf16*)(ws + 3 * SZ_T + 2 * SZ_W);
  bf16* Wob = (bf16*)(ws + 3 * SZ_T + 3 * SZ_W);
  bf16* Qh  = (bf16*)(ws + 3 * SZ_T + 4 * SZ_W);
  bf16* Kh  = (bf16*)(ws + 4 * SZ_T + 4 * SZ_W);
  bf16* Vh  = (bf16*)(ws + 5 * SZ_T + 4 * SZ_W);
  bf16* Oc  = qb;  // qb dead after projections

  CvtArgs ca;
  ca.s[0] = q;  ca.d[0] = qb;
  ca.s[1] = k;  ca.d[1] = kb;
  ca.s[2] = v;  ca.d[2] = vb;
  ca.s[3] = Wq; ca.d[3] = Wqb;
  ca.s[4] = Wk; ca.d[4] = Wkb;
  ca.s[5] = Wv; ca.d[5] = Wvb;
  ca.s[6] = Wo; ca.d[6] = Wob;
  cvt_all<<<dim3(8192), 256, 0, stream>>>(ca);

  GArgs gp = {};
  gp.A[0] = qb; gp.W[0] = Wqb; gp.bias[0] = bq; gp.Cb[0] = Qh; gp.scale[0] = QSCALE;
  gp.A[1] = kb; gp.W[1] = Wkb; gp.bias[1] = bk; gp.Cb[1] = Kh; gp.scale[1] = 1.0f;
  gp.A[2] = vb; gp.W[2] = Wvb; gp.bias[2] = bv; gp.Cb[2] = Vh; gp.scale[2] = 1.0f;
  gemm_multi<false><<<dim3(D / 64, BS / 128, 3), 256, 0, stream>>>(gp);

  attn_kernel<<<dim3(S / 128, 2 * NH), 256, 0, stream>>>(Qh, Kh, Vh, Oc);

  GArgs go = {};
  go.A[0] = Oc; go.W[0] = Wob; go.bias[0] = bo; go.Cf[0] = out; go.scale[0] = 1.0f;
  gemm_multi<true><<<dim3(D / 64, BS / 128, 1), 256, 0, stream>>>(go);
}

// Round 7
// 236.953 us; speedup vs baseline: 1.5916x; 1.0700x over previous
//
#include <hip/hip_runtime.h>
#include <stdint.h>

#define DEV __device__ __forceinline__

typedef __bf16 bf16;
typedef __bf16 bf16x8 __attribute__((ext_vector_type(8)));
typedef unsigned short u16x8 __attribute__((ext_vector_type(8)));
typedef unsigned short u16x4 __attribute__((ext_vector_type(4)));
typedef float f32x4 __attribute__((ext_vector_type(4)));
typedef uint32_t u32x4 __attribute__((ext_vector_type(4)));

static constexpr int S = 2048, D = 1024, NH = 16;
// fold 1/sqrt(DK) * log2(e) into Q so softmax runs in exp2 domain
static constexpr float QSCALE = 0.125f * 1.44269504088896340736f;
static constexpr float STHR = 4096.0f;  // partial-sum stability threshold (=2^12)

union BU { u16x8 u; bf16x8 v; };
union PU { u32x4 u; bf16x8 v; };

DEV uint32_t pack2(float a, float b) {
  union { __bf16 h; uint16_t u; } x, y;
  x.h = (__bf16)a; y.h = (__bf16)b;
  return (uint32_t)x.u | ((uint32_t)y.u << 16);
}

// ---------------- batched f32 -> bf16 convert (7 segments, 1 launch) --------
struct CvtArgs { const float* s[7]; bf16* d[7]; };
__global__ __launch_bounds__(256) void cvt_all(CvtArgs a) {
  int blk = blockIdx.x, seg, rel;
  if (blk < 6144) { seg = blk >> 11; rel = blk & 2047; }
  else { int bb = blk - 6144; seg = 3 + (bb >> 9); rel = bb & 511; }
  int i = rel * 256 + threadIdx.x;
  const float4* p = (const float4*)a.s[seg] + (size_t)i * 2;
  float4 x = p[0], y = p[1];
  bf16x8 o;
  o[0] = (bf16)x.x; o[1] = (bf16)x.y; o[2] = (bf16)x.z; o[3] = (bf16)x.w;
  o[4] = (bf16)y.x; o[5] = (bf16)y.y; o[6] = (bf16)y.z; o[7] = (bf16)y.w;
  ((bf16x8*)a.d[seg])[i] = o;
}

// ---------------- async global->LDS 16B ----------------
DEV void async_copy16(bf16* lds_dst, const bf16* g_src) {
  __builtin_amdgcn_global_load_lds(
      (const __attribute__((address_space(1))) void*)(g_src),
      (__attribute__((address_space(3))) void*)(lds_dst),
      16, 0, 0);
}

// ---------------- proj GEMM: C = A*W^T + bias, 128x128 tile (m97) ----------
struct GArgs {
  const bf16* A[3]; const bf16* W[3]; const float* bias[3];
  bf16* Cb[3]; float scale[3];
};

__global__ __launch_bounds__(256, 2)
void gemm128(GArgs g) {
  constexpr int N = 1024, K = 1024;
  const int z = blockIdx.z;
  const bf16* A = g.A[z];
  const bf16* Bt = g.W[z];
  const float* bias = g.bias[z];
  const float scale = g.scale[z];

  __shared__ bf16 As[128 * 32];
  __shared__ bf16 Bs[128 * 32];
  const int t = threadIdx.x;
  const int w = t >> 6, l = t & 63;
  const int wr = w >> 1, wc = w & 1;
  const int lr = l & 15, lg = l >> 4;
  const int m0 = blockIdx.y * 128, n0 = blockIdx.x * 128;

  f32x4 acc[4][4] = {};

  const int srow = t >> 2, scol = (t & 3) * 8;
  const bf16* Aptr = A + (size_t)(m0 + srow) * K + scol;
  const bf16* Bptr = Bt + (size_t)(n0 + srow) * K + scol;
  bf16* AsDst = &As[w * 512];
  bf16* BsDst = &Bs[w * 512];

  for (int k0 = 0; k0 < K; k0 += 32) {
    async_copy16(AsDst,        Aptr + k0);
    async_copy16(AsDst + 2048, Aptr + (size_t)64 * K + k0);
    async_copy16(BsDst,        Bptr + k0);
    async_copy16(BsDst + 2048, Bptr + (size_t)64 * K + k0);
    __syncthreads();
    bf16x8 af[4], bfr[4];
#pragma unroll
    for (int i = 0; i < 4; i++)
      af[i] = *(const bf16x8*)&As[(wr * 64 + i * 16 + lr) * 32 + lg * 8];
#pragma unroll
    for (int i = 0; i < 4; i++)
      bfr[i] = *(const bf16x8*)&Bs[(wc * 64 + i * 16 + lr) * 32 + lg * 8];
#pragma unroll
    for (int mi = 0; mi < 4; mi++)
#pragma unroll
      for (int ni = 0; ni < 4; ni++)
        acc[mi][ni] = __builtin_amdgcn_mfma_f32_16x16x32_bf16(
            af[mi], bfr[ni], acc[mi][ni], 0, 0, 0);
    __syncthreads();
  }

#pragma unroll
  for (int mi = 0; mi < 4; mi++) {
#pragma unroll
    for (int ni = 0; ni < 4; ni++) {
      int col = n0 + wc * 64 + ni * 16 + lr;
      float bv = bias[col];
#pragma unroll
      for (int r = 0; r < 4; r++) {
        int row = m0 + wr * 64 + mi * 16 + lg * 4 + r;
        g.Cb[z][(size_t)row * N + col] = (bf16)((acc[mi][ni][r] + bv) * scale);
      }
    }
  }
}

// ---------------- out GEMM: f32 out, BM=128 BN=64 ----------------
__global__ __launch_bounds__(256, 2)
void gemm64out(const bf16* __restrict__ A, const bf16* __restrict__ Bt,
               const float* __restrict__ bias, float* __restrict__ Cf) {
  constexpr int N = 1024, K = 1024;
  __shared__ bf16 As[128 * 32];
  __shared__ bf16 Bs[64 * 32];
  const int t = threadIdx.x;
  const int w = t >> 6, l = t & 63;
  const int lr = l & 15, lg = l >> 4;
  const int m0 = blockIdx.y * 128, n0 = blockIdx.x * 64;

  f32x4 acc[2][4] = {};

  const int srow = t >> 2, scol = (t & 3) * 8;
  const bf16* Aptr = A + (size_t)(m0 + srow) * K + scol;
  const bf16* Bptr = Bt + (size_t)(n0 + srow) * K + scol;
  bf16* AsDst = &As[w * 512];
  bf16* BsDst = &Bs[w * 512];

  for (int k0 = 0; k0 < K; k0 += 32) {
    async_copy16(AsDst,        Aptr + k0);
    async_copy16(AsDst + 2048, Aptr + (size_t)64 * K + k0);
    async_copy16(BsDst,        Bptr + k0);
    __syncthreads();
    bf16x8 af[2], bfr[4];
#pragma unroll
    for (int i = 0; i < 2; i++)
      af[i] = *(const bf16x8*)&As[(w * 32 + i * 16 + lr) * 32 + lg * 8];
#pragma unroll
    for (int n = 0; n < 4; n++)
      bfr[n] = *(const bf16x8*)&Bs[(n * 16 + lr) * 32 + lg * 8];
#pragma unroll
    for (int mi = 0; mi < 2; mi++)
#pragma unroll
      for (int ni = 0; ni < 4; ni++)
        acc[mi][ni] = __builtin_amdgcn_mfma_f32_16x16x32_bf16(
            af[mi], bfr[ni], acc[mi][ni], 0, 0, 0);
    __syncthreads();
  }

#pragma unroll
  for (int mi = 0; mi < 2; mi++) {
#pragma unroll
    for (int ni = 0; ni < 4; ni++) {
      int col = n0 + ni * 16 + lr;
      float bv = bias[col];
#pragma unroll
      for (int r = 0; r < 4; r++) {
        int row = m0 + w * 32 + mi * 16 + lg * 4 + r;
        Cf[(size_t)row * N + col] = acc[mi][ni][r] + bv;
      }
    }
  }
}

// ---------------- flash attention, 8 waves x 16 q-rows ----------------
// QBLK=128, KV tile 64, DK=64. K via global_load_lds with permuted+swizzled
// source (LDS linear); V reg-staged transposed+swizzled; both double-buffered;
// ONE barrier/tile. Swapped QK^T -> P lane-local. Fixed-shift softmax
// (mrun=4.0): common path has NO max tree and NO cross-lane ops; stability
// guarded by the partial sum (p_i <= s <= 2^12), slow rescale path ~never runs.
__global__ __launch_bounds__(512, 4)
void attn_kernel(const bf16* __restrict__ Qp, const bf16* __restrict__ Kp,
                 const bf16* __restrict__ Vp, bf16* __restrict__ Oc) {
  __shared__ uint4 ldsu[2048];  // 32 KB: K dbuf [0,16K), V^T dbuf [16K,32K)
  char* lds = (char*)ldsu;

  const int t = threadIdx.x, w = t >> 6, l = t & 63;
  const int lr = l & 15, lg = l >> 4;
  const int bh = blockIdx.y, b = bh >> 4, h = bh & 15;
  const int q0 = blockIdx.x * 128;
  const size_t base = (size_t)b * S * D + (size_t)h * 64;
  const size_t TILE = (size_t)64 * D;

  // Q fragments (B-operand): q row = q0 + w*16 + lr
  bf16x8 qf[2];
  {
    const bf16* qrow = Qp + base + (size_t)(q0 + w * 16 + lr) * D + lg * 8;
    qf[0] = *(const bf16x8*)(qrow);
    qf[1] = *(const bf16x8*)(qrow + 32);
  }

  f32x4 accO[4] = {};
  float mrun = 4.0f, lsum = 0.f;

  // K async source: LDS byte o = t*16 holds K[srow][seg16*8..+7],
  // rho=o>>7, seg16=((o&127)^((rho&7)<<4))>>4, srow=perm(rho).
  const bf16* kptr;
  {
    int o = t * 16;
    int rho = o >> 7;
    int seg16 = ((o & 127) ^ ((rho & 7) << 4)) >> 4;
    int mm = rho >> 4;
    int srow = ((mm & 1) << 5) | (((rho >> 2) & 3) << 3) | ((mm >> 1) << 2) | (rho & 3);
    kptr = Kp + base + (size_t)srow * D + seg16 * 8;
  }
  bf16* kdst = (bf16*)(lds + w * 1024);  // wave-uniform; HW adds lane*16B

  // V staging: thread handles kv pair (2vu,2vu+1), d cols vcc*4..+3
  const int vu = t & 31, vcc = t >> 5;
  const bf16* Vg = Vp + base + (size_t)(2 * vu) * D + vcc * 4;
  int vwa[4];
#pragma unroll
  for (int j = 0; j < 4; j++) {
    int d = vcc * 4 + j;
    vwa[j] = 16384 + ((d * 128 + vu * 4) ^ ((d & 7) << 4));
  }

  const int rswz = (lr & 7) << 4;

  // ---- prologue
  async_copy16(kdst, kptr);
  u16x4 va = *(const u16x4*)(Vg);
  u16x4 vb = *(const u16x4*)(Vg + D);
  __syncthreads();  // K(0) + V(0) loads done
#pragma unroll
  for (int j = 0; j < 4; j++)
    *(uint32_t*)(lds + vwa[j]) = (uint32_t)va[j] | ((uint32_t)vb[j] << 16);
  va = *(const u16x4*)(Vg + TILE);
  vb = *(const u16x4*)(Vg + TILE + D);
  __syncthreads();  // Vt(0) published

  const bf16* kp1 = kptr + TILE;
  const bf16* vg2 = Vg + 2 * TILE;

#pragma unroll 2
  for (int it = 0; it < 32; ++it) {
    const int cur = (it & 1) * 8192;
    const int nxt = ((it + 1) & 1) * 8192;
    const bool hasN = it < 31, hasN2 = it < 30;

    if (hasN) {
      async_copy16((bf16*)(lds + nxt + w * 1024), kp1);
      kp1 += TILE;
    }
    const bf16* pv = hasN2 ? vg2 : (Vp + base);
    u16x4 ta = *(const u16x4*)(pv);
    u16x4 tb = *(const u16x4*)(pv + D);
    vg2 += TILE;

    // ---- QK^T (swapped): sc[m] rows = kv (permuted), cols = q
    f32x4 sc[4] = {};
#pragma unroll
    for (int ks = 0; ks < 2; ks++) {
      BU kf[4];
#pragma unroll
      for (int m = 0; m < 4; m++)
        kf[m].u = *(const u16x8*)(lds + cur +
                   ((((m * 16 + lr) * 128) + ks * 64 + lg * 16) ^ rswz));
      __builtin_amdgcn_s_setprio(1);
#pragma unroll
      for (int m = 0; m < 4; m++)
        sc[m] = __builtin_amdgcn_mfma_f32_16x16x32_bf16(
            kf[m].v, qf[ks], sc[m], 0, 0, 0);
      __builtin_amdgcn_s_setprio(0);
    }

    // ---- softmax, fixed shift: p = exp2(sc - mrun); stability via sum
    float s = 0.f;
#pragma unroll
    for (int m = 0; m < 4; m++) {
      sc[m][0] = exp2f(sc[m][0] - mrun);
      sc[m][1] = exp2f(sc[m][1] - mrun);
      sc[m][2] = exp2f(sc[m][2] - mrun);
      sc[m][3] = exp2f(sc[m][3] - mrun);
      s += (sc[m][0] + sc[m][1]) + (sc[m][2] + sc[m][3]);
    }
    if (!__all(s <= STHR)) {  // rare rescale path
      float pm = sc[0][0];
#pragma unroll
      for (int m = 0; m < 4; m++)
#pragma unroll
        for (int r = 0; r < 4; r++) pm = fmaxf(pm, sc[m][r]);
      pm = fmaxf(pm, __shfl_xor(pm, 16));
      pm = fmaxf(pm, __shfl_xor(pm, 32));
      float mn = fmaxf(mrun + __log2f(pm), mrun);
      float f = exp2f(mrun - mn);
      mrun = mn;
      s *= f;
      lsum *= f;
#pragma unroll
      for (int m = 0; m < 4; m++)
#pragma unroll
        for (int r = 0; r < 4; r++) sc[m][r] *= f;
#pragma unroll
      for (int r = 0; r < 4; r++) {
        float a = __shfl(f, (lg << 4) | (lg * 4 + r));
#pragma unroll
        for (int n = 0; n < 4; n++) accO[n][r] *= a;
      }
    }
    lsum += s;
    uint32_t pk[4][2];
#pragma unroll
    for (int m = 0; m < 4; m++) {
      pk[m][0] = pack2(sc[m][0], sc[m][1]);
      pk[m][1] = pack2(sc[m][2], sc[m][3]);
    }

    // ---- publish Vt(it+1) into other buffer
    if (hasN) {
#pragma unroll
      for (int j = 0; j < 4; j++)
        *(uint32_t*)(lds + vwa[j] + nxt) = (uint32_t)va[j] | ((uint32_t)vb[j] << 16);
    }

    // ---- PV: A = P (lane-local thanks to K permutation), B = V^T tile
#pragma unroll
    for (int ks = 0; ks < 2; ks++) {
      PU pa;
      pa.u[0] = pk[ks][0];
      pa.u[1] = pk[ks][1];
      pa.u[2] = pk[2 + ks][0];
      pa.u[3] = pk[2 + ks][1];
      BU vf[4];
#pragma unroll
      for (int n = 0; n < 4; n++)
        vf[n].u = *(const u16x8*)(lds + 16384 + cur +
                   ((((n * 16 + lr) * 128) + ks * 64 + lg * 16) ^ rswz));
      __builtin_amdgcn_s_setprio(1);
#pragma unroll
      for (int n = 0; n < 4; n++)
        accO[n] = __builtin_amdgcn_mfma_f32_16x16x32_bf16(
            pa.v, vf[n].v, accO[n], 0, 0, 0);
      __builtin_amdgcn_s_setprio(0);
    }

    va = ta; vb = tb;
    __syncthreads();  // drains K copies + Vt writes; publishes tile it+1
  }

  // ---- epilogue
  lsum += __shfl_xor(lsum, 16);
  lsum += __shfl_xor(lsum, 32);
#pragma unroll
  for (int r = 0; r < 4; r++) {
    float lv = __shfl(lsum, (lg << 4) | (lg * 4 + r));
    float rl = 1.0f / lv;
    int row = q0 + w * 16 + lg * 4 + r;
    bf16* orow = Oc + base + (size_t)row * D;
#pragma unroll
    for (int n = 0; n < 4; n++) orow[n * 16 + lr] = (bf16)(accO[n][r] * rl);
  }
}

// ---------------- host ----------------
extern "C" void kernel_launch(void* const* d_in, const int* in_sizes, int n_in,
                              void* d_out, int out_size, void* d_ws, size_t ws_size,
                              hipStream_t stream) {
  const float* q  = (const float*)d_in[0];
  const float* k  = (const float*)d_in[1];
  const float* v  = (const float*)d_in[2];
  const float* Wq = (const float*)d_in[3];
  const float* bq = (const float*)d_in[4];
  const float* Wk = (const float*)d_in[5];
  const float* bk = (const float*)d_in[6];
  const float* Wv = (const float*)d_in[7];
  const float* bv = (const float*)d_in[8];
  const float* Wo = (const float*)d_in[9];
  const float* bo = (const float*)d_in[10];
  float* out = (float*)d_out;

  const int BS = 2 * S;                      // 4096 rows
  const size_t SZ_T = (size_t)BS * D * 2;    // 8 MB
  const size_t SZ_W = (size_t)D * D * 2;     // 2 MB

  char* ws = (char*)d_ws;
  bf16* qb  = (bf16*)(ws);
  bf16* kb  = (bf16*)(ws + SZ_T);
  bf16* vb  = (bf16*)(ws + 2 * SZ_T);
  bf16* Wqb = (bf16*)(ws + 3 * SZ_T);
  bf16* Wkb = (bf16*)(ws + 3 * SZ_T + SZ_W);
  bf16* Wvb = (bf16*)(ws + 3 * SZ_T + 2 * SZ_W);
  bf16* Wob = (bf16*)(ws + 3 * SZ_T + 3 * SZ_W);
  bf16* Qh  = (bf16*)(ws + 3 * SZ_T + 4 * SZ_W);
  bf16* Kh  = (bf16*)(ws + 4 * SZ_T + 4 * SZ_W);
  bf16* Vh  = (bf16*)(ws + 5 * SZ_T + 4 * SZ_W);
  bf16* Oc  = qb;  // qb dead after projections

  CvtArgs ca;
  ca.s[0] = q;  ca.d[0] = qb;
  ca.s[1] = k;  ca.d[1] = kb;
  ca.s[2] = v;  ca.d[2] = vb;
  ca.s[3] = Wq; ca.d[3] = Wqb;
  ca.s[4] = Wk; ca.d[4] = Wkb;
  ca.s[5] = Wv; ca.d[5] = Wvb;
  ca.s[6] = Wo; ca.d[6] = Wob;
  cvt_all<<<dim3(8192), 256, 0, stream>>>(ca);

  GArgs gp = {};
  gp.A[0] = qb; gp.W[0] = Wqb; gp.bias[0] = bq; gp.Cb[0] = Qh; gp.scale[0] = QSCALE;
  gp.A[1] = kb; gp.W[1] = Wkb; gp.bias[1] = bk; gp.Cb[1] = Kh; gp.scale[1] = 1.0f;
  gp.A[2] = vb; gp.W[2] = Wvb; gp.bias[2] = bv; gp.Cb[2] = Vh; gp.scale[2] = 1.0f;
  gemm128<<<dim3(D / 128, BS / 128, 3), 256, 0, stream>>>(gp);

  attn_kernel<<<dim3(S / 128, 2 * NH), 512, 0, stream>>>(Qh, Kh, Vh, Oc);

  gemm64out<<<dim3(D / 64, BS / 128), 256, 0, stream>>>(Oc, Wob, bo, out);
}

// Round 9
// 214.663 us; speedup vs baseline: 1.7569x; 1.1038x over previous
//
#include <hip/hip_runtime.h>
#include <stdint.h>

#define DEV __device__ __forceinline__

typedef __bf16 bf16;
typedef __bf16 bf16x8 __attribute__((ext_vector_type(8)));
typedef unsigned short u16x8 __attribute__((ext_vector_type(8)));
typedef unsigned short u16x4 __attribute__((ext_vector_type(4)));
typedef float f32x4 __attribute__((ext_vector_type(4)));
typedef uint32_t u32x4 __attribute__((ext_vector_type(4)));

static constexpr int S = 2048, D = 1024, NH = 16;
// fold 1/sqrt(DK) * log2(e) into Q so softmax runs in exp2 domain
static constexpr float QSCALE = 0.125f * 1.44269504088896340736f;
static constexpr float STHR = 4096.0f;  // partial-sum stability threshold (=2^12)

union BU { u16x8 u; bf16x8 v; };
union PU { u32x4 u; bf16x8 v; };

// raw v_exp_f32 (2^x), bypassing OCML's multi-inst exp2f
DEV float fexp2(float x) { return __builtin_amdgcn_exp2f(x); }

// one-inst pack of 2 f32 -> 2 bf16 (no builtin exists on gfx950; T12 recipe)
DEV uint32_t pack2(float a, float b) {
  uint32_t r;
  asm("v_cvt_pk_bf16_f32 %0, %1, %2" : "=v"(r) : "v"(a), "v"(b));
  return r;
}

// ---------------- batched f32 -> bf16 convert (7 segments, 1 launch) --------
struct CvtArgs { const float* s[7]; bf16* d[7]; };
__global__ __launch_bounds__(256) void cvt_all(CvtArgs a) {
  int blk = blockIdx.x, seg, rel;
  if (blk < 6144) { seg = blk >> 11; rel = blk & 2047; }
  else { int bb = blk - 6144; seg = 3 + (bb >> 9); rel = bb & 511; }
  int i = rel * 256 + threadIdx.x;
  const float4* p = (const float4*)a.s[seg] + (size_t)i * 2;
  float4 x = p[0], y = p[1];
  u32x4 o;
  o[0] = pack2(x.x, x.y);
  o[1] = pack2(x.z, x.w);
  o[2] = pack2(y.x, y.y);
  o[3] = pack2(y.z, y.w);
  ((u32x4*)a.d[seg])[i] = o;
}

// ---------------- async global->LDS 16B ----------------
DEV void async_copy16(bf16* lds_dst, const bf16* g_src) {
  __builtin_amdgcn_global_load_lds(
      (const __attribute__((address_space(1))) void*)(g_src),
      (__attribute__((address_space(3))) void*)(lds_dst),
      16, 0, 0);
}

// ---------------- proj GEMM: C = A*W^T + bias, 128x128 tile (m97) ----------
struct GArgs {
  const bf16* A[3]; const bf16* W[3]; const float* bias[3];
  bf16* Cb[3]; float scale[3];
};

__global__ __launch_bounds__(256, 2)
void gemm128(GArgs g) {
  constexpr int N = 1024, K = 1024;
  const int z = blockIdx.z;
  const bf16* A = g.A[z];
  const bf16* Bt = g.W[z];
  const float* bias = g.bias[z];
  const float scale = g.scale[z];

  __shared__ bf16 As[128 * 32];
  __shared__ bf16 Bs[128 * 32];
  const int t = threadIdx.x;
  const int w = t >> 6, l = t & 63;
  const int wr = w >> 1, wc = w & 1;
  const int lr = l & 15, lg = l >> 4;
  // XCD-aware swizzle: 256 blocks/z, 8 XCDs -> chunk of 32 per XCD
  // (4 contiguous m-panels = 1MB A + full W 2MB fit one XCD's 4MB L2)
  const int orig = blockIdx.x + (blockIdx.y << 3);
  const int tl = ((orig & 7) << 5) | (orig >> 3);
  const int m0 = (tl >> 3) * 128, n0 = (tl & 7) * 128;

  f32x4 acc[4][4] = {};

  const int srow = t >> 2, scol = (t & 3) * 8;
  const bf16* Aptr = A + (size_t)(m0 + srow) * K + scol;
  const bf16* Bptr = Bt + (size_t)(n0 + srow) * K + scol;
  bf16* AsDst = &As[w * 512];
  bf16* BsDst = &Bs[w * 512];

  for (int k0 = 0; k0 < K; k0 += 32) {
    async_copy16(AsDst,        Aptr + k0);
    async_copy16(AsDst + 2048, Aptr + (size_t)64 * K + k0);
    async_copy16(BsDst,        Bptr + k0);
    async_copy16(BsDst + 2048, Bptr + (size_t)64 * K + k0);
    __syncthreads();
    bf16x8 af[4], bfr[4];
#pragma unroll
    for (int i = 0; i < 4; i++)
      af[i] = *(const bf16x8*)&As[(wr * 64 + i * 16 + lr) * 32 + lg * 8];
#pragma unroll
    for (int i = 0; i < 4; i++)
      bfr[i] = *(const bf16x8*)&Bs[(wc * 64 + i * 16 + lr) * 32 + lg * 8];
#pragma unroll
    for (int mi = 0; mi < 4; mi++)
#pragma unroll
      for (int ni = 0; ni < 4; ni++)
        acc[mi][ni] = __builtin_amdgcn_mfma_f32_16x16x32_bf16(
            af[mi], bfr[ni], acc[mi][ni], 0, 0, 0);
    __syncthreads();
  }

#pragma unroll
  for (int mi = 0; mi < 4; mi++) {
#pragma unroll
    for (int ni = 0; ni < 4; ni++) {
      int col = n0 + wc * 64 + ni * 16 + lr;
      float bv = bias[col];
#pragma unroll
      for (int r = 0; r < 4; r++) {
        int row = m0 + wr * 64 + mi * 16 + lg * 4 + r;
        uint32_t pk = pack2((acc[mi][ni][r] + bv) * scale, 0.f);
        *(uint16_t*)&g.Cb[z][(size_t)row * N + col] = (uint16_t)pk;
      }
    }
  }
}

// ---------------- out GEMM: f32 out, BM=128 BN=64 ----------------
__global__ __launch_bounds__(256, 2)
void gemm64out(const bf16* __restrict__ A, const bf16* __restrict__ Bt,
               const float* __restrict__ bias, float* __restrict__ Cf) {
  constexpr int N = 1024, K = 1024;
  __shared__ bf16 As[128 * 32];
  __shared__ bf16 Bs[64 * 32];
  const int t = threadIdx.x;
  const int w = t >> 6, l = t & 63;
  const int lr = l & 15, lg = l >> 4;
  // XCD swizzle: 512 blocks -> chunk of 64/XCD (4 m-panels + full W in L2)
  const int orig = blockIdx.x + (blockIdx.y << 4);
  const int tl = ((orig & 7) << 6) | (orig >> 3);
  const int m0 = (tl >> 4) * 128, n0 = (tl & 15) * 64;

  f32x4 acc[2][4] = {};

  const int srow = t >> 2, scol = (t & 3) * 8;
  const bf16* Aptr = A + (size_t)(m0 + srow) * K + scol;
  const bf16* Bptr = Bt + (size_t)(n0 + srow) * K + scol;
  bf16* AsDst = &As[w * 512];
  bf16* BsDst = &Bs[w * 512];

  for (int k0 = 0; k0 < K; k0 += 32) {
    async_copy16(AsDst,        Aptr + k0);
    async_copy16(AsDst + 2048, Aptr + (size_t)64 * K + k0);
    async_copy16(BsDst,        Bptr + k0);
    __syncthreads();
    bf16x8 af[2], bfr[4];
#pragma unroll
    for (int i = 0; i < 2; i++)
      af[i] = *(const bf16x8*)&As[(w * 32 + i * 16 + lr) * 32 + lg * 8];
#pragma unroll
    for (int n = 0; n < 4; n++)
      bfr[n] = *(const bf16x8*)&Bs[(n * 16 + lr) * 32 + lg * 8];
#pragma unroll
    for (int mi = 0; mi < 2; mi++)
#pragma unroll
      for (int ni = 0; ni < 4; ni++)
        acc[mi][ni] = __builtin_amdgcn_mfma_f32_16x16x32_bf16(
            af[mi], bfr[ni], acc[mi][ni], 0, 0, 0);
    __syncthreads();
  }

#pragma unroll
  for (int mi = 0; mi < 2; mi++) {
#pragma unroll
    for (int ni = 0; ni < 4; ni++) {
      int col = n0 + ni * 16 + lr;
      float bv = bias[col];
#pragma unroll
      for (int r = 0; r < 4; r++) {
        int row = m0 + w * 32 + mi * 16 + lg * 4 + r;
        Cf[(size_t)row * N + col] = acc[mi][ni][r] + bv;
      }
    }
  }
}

// ---------------- flash attention, 8 waves x 16 q-rows ----------------
// QBLK=128, KV tile 64, DK=64. K via global_load_lds with permuted+swizzled
// source (LDS linear); V reg-staged transposed+swizzled; both double-buffered;
// ONE barrier per tile. Swapped QK^T -> P lane-local. Fixed-shift softmax
// (raw v_exp_f32, v_cvt_pk_bf16_f32): common path has NO max tree, NO
// cross-lane ops, 1-inst exp and 1-inst pack. Stability via partial-sum guard.
__global__ __launch_bounds__(512, 4)
void attn_kernel(const bf16* __restrict__ Qp, const bf16* __restrict__ Kp,
                 const bf16* __restrict__ Vp, bf16* __restrict__ Oc) {
  __shared__ uint4 ldsu[2048];  // 32 KB: K dbuf [0,16K), V^T dbuf [16K,32K)
  char* lds = (char*)ldsu;

  const int t = threadIdx.x, w = t >> 6, l = t & 63;
  const int lr = l & 15, lg = l >> 4;
  // XCD swizzle: 512 blocks (16 q-blk x 32 bh) -> 64/XCD = 4 heads' K/V (2MB)
  const int orig = blockIdx.x + (blockIdx.y << 4);
  const int tl = ((orig & 7) << 6) | (orig >> 3);
  const int qblk = tl & 15, bh = tl >> 4;
  const int b = bh >> 4, h = bh & 15;
  const int q0 = qblk * 128;
  const size_t base = (size_t)b * S * D + (size_t)h * 64;
  const size_t TILE = (size_t)64 * D;

  // Q fragments (B-operand): q row = q0 + w*16 + lr
  bf16x8 qf[2];
  {
    const bf16* qrow = Qp + base + (size_t)(q0 + w * 16 + lr) * D + lg * 8;
    qf[0] = *(const bf16x8*)(qrow);
    qf[1] = *(const bf16x8*)(qrow + 32);
  }

  f32x4 accO[4] = {};
  float mrun = 4.0f, lsum = 0.f;

  // K async source: LDS byte o = t*16 holds K[srow][seg16*8..+7],
  // rho=o>>7, seg16=((o&127)^((rho&7)<<4))>>4, srow=perm(rho).
  const bf16* kptr;
  {
    int o = t * 16;
    int rho = o >> 7;
    int seg16 = ((o & 127) ^ ((rho & 7) << 4)) >> 4;
    int mm = rho >> 4;
    int srow = ((mm & 1) << 5) | (((rho >> 2) & 3) << 3) | ((mm >> 1) << 2) | (rho & 3);
    kptr = Kp + base + (size_t)srow * D + seg16 * 8;
  }
  bf16* kdst = (bf16*)(lds + w * 1024);  // wave-uniform; HW adds lane*16B

  // V staging: thread handles kv pair (2vu,2vu+1), d cols vcc*4..+3
  const int vu = t & 31, vcc = t >> 5;
  const bf16* Vg = Vp + base + (size_t)(2 * vu) * D + vcc * 4;
  int vwa[4];
#pragma unroll
  for (int j = 0; j < 4; j++) {
    int d = vcc * 4 + j;
    vwa[j] = 16384 + ((d * 128 + vu * 4) ^ ((d & 7) << 4));
  }

  const int rswz = (lr & 7) << 4;

  // ---- prologue
  async_copy16(kdst, kptr);
  u16x4 va = *(const u16x4*)(Vg);
  u16x4 vb = *(const u16x4*)(Vg + D);
  __syncthreads();  // K(0) + V(0) loads done
#pragma unroll
  for (int j = 0; j < 4; j++)
    *(uint32_t*)(lds + vwa[j]) = (uint32_t)va[j] | ((uint32_t)vb[j] << 16);
  va = *(const u16x4*)(Vg + TILE);
  vb = *(const u16x4*)(Vg + TILE + D);
  __syncthreads();  // Vt(0) published

  const bf16* kp1 = kptr + TILE;
  const bf16* vg2 = Vg + 2 * TILE;

#pragma unroll 2
  for (int it = 0; it < 32; ++it) {
    const int cur = (it & 1) * 8192;
    const int nxt = ((it + 1) & 1) * 8192;
    const bool hasN = it < 31, hasN2 = it < 30;

    if (hasN) {
      async_copy16((bf16*)(lds + nxt + w * 1024), kp1);
      kp1 += TILE;
    }
    const bf16* pv = hasN2 ? vg2 : (Vp + base);
    u16x4 ta = *(const u16x4*)(pv);
    u16x4 tb = *(const u16x4*)(pv + D);
    vg2 += TILE;

    // ---- QK^T (swapped): sc[m] rows = kv (permuted), cols = q
    f32x4 sc[4] = {};
#pragma unroll
    for (int ks = 0; ks < 2; ks++) {
      BU kf[4];
#pragma unroll
      for (int m = 0; m < 4; m++)
        kf[m].u = *(const u16x8*)(lds + cur +
                   ((((m * 16 + lr) * 128) + ks * 64 + lg * 16) ^ rswz));
      __builtin_amdgcn_s_setprio(1);
#pragma unroll
      for (int m = 0; m < 4; m++)
        sc[m] = __builtin_amdgcn_mfma_f32_16x16x32_bf16(
            kf[m].v, qf[ks], sc[m], 0, 0, 0);
      __builtin_amdgcn_s_setprio(0);
    }

    // ---- softmax, fixed shift: p = exp2(sc - mrun), 1-inst exp
    float s = 0.f;
#pragma unroll
    for (int m = 0; m < 4; m++) {
      sc[m][0] = fexp2(sc[m][0] - mrun);
      sc[m][1] = fexp2(sc[m][1] - mrun);
      sc[m][2] = fexp2(sc[m][2] - mrun);
      sc[m][3] = fexp2(sc[m][3] - mrun);
      s += (sc[m][0] + sc[m][1]) + (sc[m][2] + sc[m][3]);
    }
    if (!__all(s <= STHR)) {  // rare rescale path
      float pm = sc[0][0];
#pragma unroll
      for (int m = 0; m < 4; m++)
#pragma unroll
        for (int r = 0; r < 4; r++) pm = fmaxf(pm, sc[m][r]);
      pm = fmaxf(pm, __shfl_xor(pm, 16));
      pm = fmaxf(pm, __shfl_xor(pm, 32));
      float mn = fmaxf(mrun + __log2f(pm), mrun);
      float f = fexp2(mrun - mn);
      mrun = mn;
      s *= f;
      lsum *= f;
#pragma unroll
      for (int m = 0; m < 4; m++)
#pragma unroll
        for (int r = 0; r < 4; r++) sc[m][r] *= f;
#pragma unroll
      for (int r = 0; r < 4; r++) {
        float a = __shfl(f, (lg << 4) | (lg * 4 + r));
#pragma unroll
        for (int n = 0; n < 4; n++) accO[n][r] *= a;
      }
    }
    lsum += s;
    uint32_t pk[4][2];
#pragma unroll
    for (int m = 0; m < 4; m++) {
      pk[m][0] = pack2(sc[m][0], sc[m][1]);
      pk[m][1] = pack2(sc[m][2], sc[m][3]);
    }

    // ---- publish Vt(it+1) into other buffer
    if (hasN) {
#pragma unroll
      for (int j = 0; j < 4; j++)
        *(uint32_t*)(lds + vwa[j] + nxt) = (uint32_t)va[j] | ((uint32_t)vb[j] << 16);
    }

    // ---- PV: A = P (lane-local thanks to K permutation), B = V^T tile
#pragma unroll
    for (int ks = 0; ks < 2; ks++) {
      PU pa;
      pa.u[0] = pk[ks][0];
      pa.u[1] = pk[ks][1];
      pa.u[2] = pk[2 + ks][0];
      pa.u[3] = pk[2 + ks][1];
      BU vf[4];
#pragma unroll
      for (int n = 0; n < 4; n++)
        vf[n].u = *(const u16x8*)(lds + 16384 + cur +
                   ((((n * 16 + lr) * 128) + ks * 64 + lg * 16) ^ rswz));
      __builtin_amdgcn_s_setprio(1);
#pragma unroll
      for (int n = 0; n < 4; n++)
        accO[n] = __builtin_amdgcn_mfma_f32_16x16x32_bf16(
            pa.v, vf[n].v, accO[n], 0, 0, 0);
      __builtin_amdgcn_s_setprio(0);
    }

    va = ta; vb = tb;
    __syncthreads();  // drains K copies + Vt writes; publishes tile it+1
  }

  // ---- epilogue
  lsum += __shfl_xor(lsum, 16);
  lsum += __shfl_xor(lsum, 32);
#pragma unroll
  for (int r = 0; r < 4; r++) {
    float lv = __shfl(lsum, (lg << 4) | (lg * 4 + r));
    float rl = 1.0f / lv;
    int row = q0 + w * 16 + lg * 4 + r;
    bf16* orow = Oc + base + (size_t)row * D;
#pragma unroll
    for (int n = 0; n < 4; n++) {
      uint32_t pkv = pack2(accO[n][r] * rl, 0.f);
      *(uint16_t*)&orow[n * 16 + lr] = (uint16_t)pkv;
    }
  }
}

// ---------------- host ----------------
extern "C" void kernel_launch(void* const* d_in, const int* in_sizes, int n_in,
                              void* d_out, int out_size, void* d_ws, size_t ws_size,
                              hipStream_t stream) {
  const float* q  = (const float*)d_in[0];
  const float* k  = (const float*)d_in[1];
  const float* v  = (const float*)d_in[2];
  const float* Wq = (const float*)d_in[3];
  const float* bq = (const float*)d_in[4];
  const float* Wk = (const float*)d_in[5];
  const float* bk = (const float*)d_in[6];
  const float* Wv = (const float*)d_in[7];
  const float* bv = (const float*)d_in[8];
  const float* Wo = (const float*)d_in[9];
  const float* bo = (const float*)d_in[10];
  float* out = (float*)d_out;

  const int BS = 2 * S;                      // 4096 rows
  const size_t SZ_T = (size_t)BS * D * 2;    // 8 MB
  const size_t SZ_W = (size_t)D * D * 2;     // 2 MB

  char* ws = (char*)d_ws;
  bf16* qb  = (bf16*)(ws);
  bf16* kb  = (bf16*)(ws + SZ_T);
  bf16* vb  = (bf16*)(ws + 2 * SZ_T);
  bf16* Wqb = (bf16*)(ws + 3 * SZ_T);
  bf16* Wkb = (bf16*)(ws + 3 * SZ_T + SZ_W);
  bf16* Wvb = (bf16*)(ws + 3 * SZ_T + 2 * SZ_W);
  bf16* Wob = (bf16*)(ws + 3 * SZ_T + 3 * SZ_W);
  bf16* Qh  = (bf16*)(ws + 3 * SZ_T + 4 * SZ_W);
  bf16* Kh  = (bf16*)(ws + 4 * SZ_T + 4 * SZ_W);
  bf16* Vh  = (bf16*)(ws + 5 * SZ_T + 4 * SZ_W);
  bf16* Oc  = qb;  // qb dead after projections

  CvtArgs ca;
  ca.s[0] = q;  ca.d[0] = qb;
  ca.s[1] = k;  ca.d[1] = kb;
  ca.s[2] = v;  ca.d[2] = vb;
  ca.s[3] = Wq; ca.d[3] = Wqb;
  ca.s[4] = Wk; ca.d[4] = Wkb;
  ca.s[5] = Wv; ca.d[5] = Wvb;
  ca.s[6] = Wo; ca.d[6] = Wob;
  cvt_all<<<dim3(8192), 256, 0, stream>>>(ca);

  GArgs gp = {};
  gp.A[0] = qb; gp.W[0] = Wqb; gp.bias[0] = bq; gp.Cb[0] = Qh; gp.scale[0] = QSCALE;
  gp.A[1] = kb; gp.W[1] = Wkb; gp.bias[1] = bk; gp.Cb[1] = Kh; gp.scale[1] = 1.0f;
  gp.A[2] = vb; gp.W[2] = Wvb; gp.bias[2] = bv; gp.Cb[2] = Vh; gp.scale[2] = 1.0f;
  gemm128<<<dim3(D / 128, BS / 128, 3), 256, 0, stream>>>(gp);

  attn_kernel<<<dim3(S / 128, 2 * NH), 512, 0, stream>>>(Qh, Kh, Vh, Oc);

  gemm64out<<<dim3(D / 64, BS / 128), 256, 0, stream>>>(Oc, Wob, bo, out);
}